// Round 3
// baseline (321.723 us; speedup 1.0000x reference)
//
#include <hip/hip_runtime.h>

#define BB 4
#define CCH 384
#define HH 56
#define WWD 56
#define HW 3136
#define S2 49
#define S2P 52
#define D2 192
#define K2 25
#define XSP 20          // xs leading dim (==52 mod 32 -> conflict-free pattern)

// ---- Kernel 1: GT[i][j] = sum_d Wk[d][i] * Wq[d][j]   (384x384, K=192) ----
__global__ __launch_bounds__(256, 4) void gt_k(const float* __restrict__ Wk,
                                               const float* __restrict__ Wq,
                                               float* __restrict__ GT) {
    __shared__ float As[D2 * 16];
    __shared__ float Bs[D2 * 16];
    int bi = blockIdx.x % 24, bj = blockIdx.x / 24;
    int t = threadIdx.x;
    int tj = t & 15, ti = t >> 4;
    // stage: 192x16 each = 768 float4; 3 per thread, exact
#pragma unroll
    for (int k = 0; k < 3; k++) {
        int idx = t + 256 * k;
        int d = idx >> 2, q = idx & 3;
        *(float4*)&As[idx * 4] = *(const float4*)&Wk[(size_t)d * CCH + bi * 16 + 4 * q];
        *(float4*)&Bs[idx * 4] = *(const float4*)&Wq[(size_t)d * CCH + bj * 16 + 4 * q];
    }
    __syncthreads();
    float acc = 0.f;
#pragma unroll 8
    for (int d = 0; d < D2; d++)
        acc += As[d * 16 + ti] * Bs[d * 16 + tj];
    GT[(size_t)(bi * 16 + ti) * CCH + bj * 16 + tj] = acc;
}

// ---- Kernel 2: per (b,s): v = avgpool64(ctx bin), M[b,:,s] = GT^T v ----
__global__ __launch_bounds__(384) void mv_k(const float* __restrict__ ctx,
                                            const float* __restrict__ GT,
                                            float* __restrict__ M) {
    __shared__ float v[CCH];
    int b = blockIdx.x / S2, s = blockIdx.x % S2;
    int t = threadIdx.x;
    int sy = s / 7, sx = s % 7;
    // phase 1: thread c pools its 8x8 bin
    {
        const float* p = ctx + ((size_t)(b * CCH + t)) * HW + sy * 8 * WWD + sx * 8;
        float sum = 0.f;
#pragma unroll
        for (int r = 0; r < 8; r++) {
            float4 a = *(const float4*)(p + r * WWD);
            float4 c = *(const float4*)(p + r * WWD + 4);
            sum += a.x + a.y + a.z + a.w + c.x + c.y + c.z + c.w;
        }
        v[t] = sum * (1.f / 64.f);
    }
    __syncthreads();
    // phase 2: M[b][j][s] = sum_i v[i] * GT[i][j], j = t (coalesced GT rows)
    float acc = 0.f;
#pragma unroll 8
    for (int i = 0; i < CCH; i++)
        acc += v[i] * GT[(size_t)i * CCH + t];
    M[((size_t)(b * CCH + t)) * S2P + s] = acc;
    if (s < 3) M[((size_t)(b * CCH + t)) * S2P + 49 + s] = 0.f;
}

// ---- Kernel 3: scores = x^T M (16-way K-split), softmax(49), dyn = Wwd*A ----
// 256 thr, 16 px/block, grid B*196. Roles: pxg=t&3, sg=(t>>2)&3, slice=t>>4.
__global__ __launch_bounds__(256, 4) void attn_k(const float* __restrict__ x,
                                                 const float* __restrict__ M,
                                                 const float* __restrict__ Wwd,
                                                 float* __restrict__ dyn) {
    __shared__ __align__(16) float smem[96 * XSP + 96 * S2P];  // xs | Ms ; red aliases
    __shared__ __align__(16) float sc[16 * S2P];
    __shared__ __align__(16) float wl[K2 * S2P];
    float* xs  = smem;               // [96][20]
    float* Ms  = smem + 96 * XSP;    // [96][52]
    float* red = smem;               // [4][16][52] = 3328 <= 1920 ok? no: 3328 < 6912 total, aliases xs+part of Ms

    int b  = blockIdx.x / 196;
    int n0 = (blockIdx.x % 196) * 16;
    int t  = threadIdx.x;
    int pxg = t & 3, sg = (t >> 2) & 3, slice = t >> 4;

    float4 acc4[4][4];
#pragma unroll
    for (int k = 0; k < 4; k++)
#pragma unroll
        for (int j = 0; j < 4; j++) acc4[k][j] = make_float4(0.f, 0.f, 0.f, 0.f);

    const float* xb = x + (size_t)b * CCH * HW + n0;
    const float* Mb = M + (size_t)b * CCH * S2P;

    for (int ch = 0; ch < 4; ch++) {
        int c0 = ch * 96;
        // stage xs: 384 f4, fixed unroll (256 + 128)
        {
            int idx = t;
            int r = idx >> 2, cq = idx & 3;
            float4 val = *(const float4*)&xb[(size_t)(c0 + r) * HW + 4 * cq];
            *(float4*)&xs[r * XSP + 4 * cq] = val;
            if (t < 128) {
                int idx2 = t + 256;
                int r2 = idx2 >> 2, cq2 = idx2 & 3;
                float4 v2 = *(const float4*)&xb[(size_t)(c0 + r2) * HW + 4 * cq2];
                *(float4*)&xs[r2 * XSP + 4 * cq2] = v2;
            }
        }
        // stage Ms: 1248 f4 = 4*256 + 224, fixed unroll
        {
            const float* src = Mb + (size_t)c0 * S2P;
#pragma unroll
            for (int k = 0; k < 4; k++) {
                int idx = t + 256 * k;
                *(float4*)&Ms[4 * idx] = *(const float4*)&src[4 * idx];
            }
            if (t < 224) {
                int idx = t + 1024;
                *(float4*)&Ms[4 * idx] = *(const float4*)&src[4 * idx];
            }
        }
        __syncthreads();
        int rbase = 6 * slice;
#pragma unroll
        for (int m = 0; m < 6; m++) {
            int r = rbase + m;
            const float4 xv = *(const float4*)&xs[r * XSP + 4 * pxg];
#pragma unroll
            for (int k = 0; k < 3; k++) {
                int g = sg + 4 * k;
                const float4 mv = *(const float4*)&Ms[r * S2P + 4 * g];
                acc4[k][0].x += mv.x * xv.x; acc4[k][0].y += mv.x * xv.y;
                acc4[k][0].z += mv.x * xv.z; acc4[k][0].w += mv.x * xv.w;
                acc4[k][1].x += mv.y * xv.x; acc4[k][1].y += mv.y * xv.y;
                acc4[k][1].z += mv.y * xv.z; acc4[k][1].w += mv.y * xv.w;
                acc4[k][2].x += mv.z * xv.x; acc4[k][2].y += mv.z * xv.y;
                acc4[k][2].z += mv.z * xv.z; acc4[k][2].w += mv.z * xv.w;
                acc4[k][3].x += mv.w * xv.x; acc4[k][3].y += mv.w * xv.y;
                acc4[k][3].z += mv.w * xv.z; acc4[k][3].w += mv.w * xv.w;
            }
            if (sg == 0) {
                const float4 mv = *(const float4*)&Ms[r * S2P + 48];
                acc4[3][0].x += mv.x * xv.x; acc4[3][0].y += mv.x * xv.y;
                acc4[3][0].z += mv.x * xv.z; acc4[3][0].w += mv.x * xv.w;
                acc4[3][1].x += mv.y * xv.x; acc4[3][1].y += mv.y * xv.y;
                acc4[3][1].z += mv.y * xv.z; acc4[3][1].w += mv.y * xv.w;
                acc4[3][2].x += mv.z * xv.x; acc4[3][2].y += mv.z * xv.y;
                acc4[3][2].z += mv.z * xv.z; acc4[3][2].w += mv.z * xv.w;
                acc4[3][3].x += mv.w * xv.x; acc4[3][3].y += mv.w * xv.y;
                acc4[3][3].z += mv.w * xv.z; acc4[3][3].w += mv.w * xv.w;
            }
        }
        __syncthreads();
    }

    // in-wave reduce across 4 slice-groups (lane^16, lane^32)
#pragma unroll
    for (int k = 0; k < 4; k++)
#pragma unroll
        for (int j = 0; j < 4; j++) {
            acc4[k][j].x += __shfl_xor(acc4[k][j].x, 16);
            acc4[k][j].y += __shfl_xor(acc4[k][j].y, 16);
            acc4[k][j].z += __shfl_xor(acc4[k][j].z, 16);
            acc4[k][j].w += __shfl_xor(acc4[k][j].w, 16);
            acc4[k][j].x += __shfl_xor(acc4[k][j].x, 32);
            acc4[k][j].y += __shfl_xor(acc4[k][j].y, 32);
            acc4[k][j].z += __shfl_xor(acc4[k][j].z, 32);
            acc4[k][j].w += __shfl_xor(acc4[k][j].w, 32);
        }

    // wave partials -> red[wave][16px][52]
    if ((t & 63) < 16) {
        int wv = t >> 6;
        float* rb = red + (size_t)wv * 16 * S2P;
#pragma unroll
        for (int k = 0; k < 4; k++) {
            int g = sg + 4 * k;
            if (g < 13) {
                *(float4*)&rb[(4 * pxg + 0) * S2P + 4 * g] =
                    make_float4(acc4[k][0].x, acc4[k][1].x, acc4[k][2].x, acc4[k][3].x);
                *(float4*)&rb[(4 * pxg + 1) * S2P + 4 * g] =
                    make_float4(acc4[k][0].y, acc4[k][1].y, acc4[k][2].y, acc4[k][3].y);
                *(float4*)&rb[(4 * pxg + 2) * S2P + 4 * g] =
                    make_float4(acc4[k][0].z, acc4[k][1].z, acc4[k][2].z, acc4[k][3].z);
                *(float4*)&rb[(4 * pxg + 3) * S2P + 4 * g] =
                    make_float4(acc4[k][0].w, acc4[k][1].w, acc4[k][2].w, acc4[k][3].w);
            }
        }
    }
    __syncthreads();

    // final reduce over 4 waves -> sc
    if (t < 208) {
        int px = t / 13, q = t - px * 13;
        float4 ssum = make_float4(0.f, 0.f, 0.f, 0.f);
#pragma unroll
        for (int wv = 0; wv < 4; wv++) {
            float4 vv = *(float4*)&red[(size_t)(wv * 16 + px) * S2P + 4 * q];
            ssum.x += vv.x; ssum.y += vv.y; ssum.z += vv.z; ssum.w += vv.w;
        }
        *(float4*)&sc[px * S2P + 4 * q] = ssum;
    }
    __syncthreads();

    // softmax (threads < 128: 8 lanes per pixel) | Wwd staging (threads >= 128)
    if (t < 128) {
        int px = t >> 3, li = t & 7;
        float mx = -3.4e38f;
#pragma unroll
        for (int k = 0; k < 7; k++) { int s = li + 8 * k; if (s < S2) mx = fmaxf(mx, sc[px * S2P + s]); }
        mx = fmaxf(mx, __shfl_xor(mx, 1, 8));
        mx = fmaxf(mx, __shfl_xor(mx, 2, 8));
        mx = fmaxf(mx, __shfl_xor(mx, 4, 8));
        float e[7]; float sum = 0.f;
#pragma unroll
        for (int k = 0; k < 7; k++) {
            int s = li + 8 * k;
            if (s < S2) { e[k] = __expf(sc[px * S2P + s] - mx); sum += e[k]; }
        }
        sum += __shfl_xor(sum, 1, 8);
        sum += __shfl_xor(sum, 2, 8);
        sum += __shfl_xor(sum, 4, 8);
        float inv = 1.f / sum;
#pragma unroll
        for (int k = 0; k < 7; k++) {
            int s = li + 8 * k;
            if (s < S2) sc[px * S2P + s] = e[k] * inv;
        }
    } else {
        int u = t - 128;
#pragma unroll
        for (int k = 0; k < 10; k++) {
            int i = u + 128 * k;
            int j = i / S2P, ss = i - j * S2P;
            wl[i] = (ss < S2) ? Wwd[j * S2 + ss] : 0.f;
        }
        if (u < 20) {
            int i = u + 1280;
            int j = i / S2P, ss = i - j * S2P;
            wl[i] = (ss < S2) ? Wwd[j * S2 + ss] : 0.f;
        }
    }
    __syncthreads();

    // dyn[b,j,n0+px] = sum_s wl[j,s]*sc[px,s]   (400 outs: 256 + 144)
    float* dynb = dyn + (size_t)b * K2 * HW + n0;
#pragma unroll
    for (int pass = 0; pass < 2; pass++) {
        int o = t + 256 * pass;
        if (pass == 0 || t < 144) {
            int j = o >> 4, px = o & 15;
            float a = 0.f;
#pragma unroll
            for (int q = 0; q < 13; q++) {
                float4 wv = *(float4*)&wl[j * S2P + 4 * q];
                float4 pv = *(float4*)&sc[px * S2P + 4 * q];
                a += wv.x * pv.x + wv.y * pv.y + wv.z * pv.z + wv.w * pv.w;
            }
            dynb[(size_t)j * HW + px] = a;
        }
    }
}

// ---- Kernel 4: 5x5 dynamic stencil; 16 ch x 8-row stripe; 2 rows/thread ----
__global__ __launch_bounds__(256, 3) void out_k(const float* __restrict__ x,
                                                const float* __restrict__ dyn,
                                                float* __restrict__ out) {
    __shared__ float xt[16][12][60];
    int blk    = blockIdx.x;
    int stripe = blk % 7;
    int cg     = (blk / 7) % 24;
    int b      = blk / (7 * 24);
    int h0 = stripe * 8;
    int c0 = cg * 16;
    int t  = threadIdx.x;
    const float* xb = x + ((size_t)(b * CCH + c0)) * HW;

    // zero halo columns 0,1,58,59 (x cols -2,-1,56,57 are always OOB)
    if (t < 192) {
        int cc = t / 12, r = t % 12;
        xt[cc][r][0] = 0.f; xt[cc][r][1] = 0.f;
        xt[cc][r][58] = 0.f; xt[cc][r][59] = 0.f;
    }
    // interior: 16*12 rows x 14 f4 = 2688 f4 (10*256 + 128)
#pragma unroll
    for (int k = 0; k < 11; k++) {
        int idx = t + 256 * k;
        if (k < 10 || t < 128) {
            int cc  = idx / 168;
            int rem = idx - cc * 168;
            int r   = rem / 14;
            int q   = rem - r * 14;
            int h   = h0 - 2 + r;
            float4 v = make_float4(0.f, 0.f, 0.f, 0.f);
            if ((unsigned)h < (unsigned)HH)
                v = *(const float4*)&xb[(size_t)cc * HW + h * WWD + 4 * q];
            xt[cc][r][2 + 4 * q + 0] = v.x;
            xt[cc][r][2 + 4 * q + 1] = v.y;
            xt[cc][r][2 + 4 * q + 2] = v.z;
            xt[cc][r][2 + 4 * q + 3] = v.w;
        }
    }

    bool act = t < 224;
    int w = t % 56;
    int u = t / 56;                  // 0..3 -> rows 2u, 2u+1
    int n = (h0 + 2 * u) * WWD + w;
    float dv0[K2], dv1[K2];
    if (act) {
        const float* db = dyn + (size_t)b * K2 * HW + n;
#pragma unroll
        for (int j = 0; j < K2; j++) {
            dv0[j] = db[(size_t)j * HW];
            dv1[j] = db[(size_t)j * HW + WWD];
        }
    }
    __syncthreads();
    if (!act) return;

    float* ob = out + ((size_t)(b * CCH + c0)) * HW + n;
#pragma unroll
    for (int cc = 0; cc < 16; cc++) {
        float a0 = 0.f, a1 = 0.f;
#pragma unroll
        for (int rr = 0; rr < 6; rr++) {
            int lr = 2 * u + rr;
            float v0 = xt[cc][lr][w + 0];
            float v1 = xt[cc][lr][w + 1];
            float v2 = xt[cc][lr][w + 2];
            float v3 = xt[cc][lr][w + 3];
            float v4 = xt[cc][lr][w + 4];
            if (rr < 5) {
                int o5 = rr * 5;
                a0 += v0 * dv0[o5] + v1 * dv0[o5 + 1] + v2 * dv0[o5 + 2]
                    + v3 * dv0[o5 + 3] + v4 * dv0[o5 + 4];
            }
            if (rr >= 1) {
                int o5 = (rr - 1) * 5;
                a1 += v0 * dv1[o5] + v1 * dv1[o5 + 1] + v2 * dv1[o5 + 2]
                    + v3 * dv1[o5 + 3] + v4 * dv1[o5 + 4];
            }
        }
        ob[(size_t)cc * HW] = a0;
        ob[(size_t)cc * HW + WWD] = a1;
    }
}

extern "C" void kernel_launch(void* const* d_in, const int* in_sizes, int n_in,
                              void* d_out, int out_size, void* d_ws, size_t ws_size,
                              hipStream_t stream) {
    const float* x   = (const float*)d_in[0];
    const float* ctx = (const float*)d_in[1];
    const float* Wq  = (const float*)d_in[2];
    const float* Wk  = (const float*)d_in[3];
    const float* Wwd = (const float*)d_in[4];
    float* out = (float*)d_out;
    float* ws  = (float*)d_ws;

    float* GT  = ws;                    // 384*384            = 147456
    float* M   = ws + 147456;           // B*384*52           =  79872
    float* dyn = ws + 147456 + 79872;   // B*25*3136          = 313600

    gt_k<<<24 * 24, 256, 0, stream>>>(Wk, Wq, GT);
    mv_k<<<BB * S2, 384, 0, stream>>>(ctx, GT, M);
    attn_k<<<BB * 196, 256, 0, stream>>>(x, M, Wwd, dyn);
    out_k<<<BB * 24 * 7, 256, 0, stream>>>(x, dyn, out);
}

// Round 4
// 163.563 us; speedup vs baseline: 1.9670x; 1.9670x over previous
//
#include <hip/hip_runtime.h>

#define BB 4
#define CCH 384
#define HH 56
#define WWD 56
#define HW 3136
#define S2 49
#define S2P 52
#define D2 192
#define K2 25
#define XSP 20          // xs leading dim (==52 mod 32 -> conflict-free pattern)

// ---- Kernel 1: GT[i][j] = sum_d Wk[d][i] * Wq[d][j]   (384x384, K=192) ----
__global__ __launch_bounds__(256) void gt_k(const float* __restrict__ Wk,
                                            const float* __restrict__ Wq,
                                            float* __restrict__ GT) {
    __shared__ float As[D2 * 16];
    __shared__ float Bs[D2 * 16];
    int bi = blockIdx.x % 24, bj = blockIdx.x / 24;
    int t = threadIdx.x;
    int tj = t & 15, ti = t >> 4;
#pragma unroll
    for (int k = 0; k < 3; k++) {
        int idx = t + 256 * k;
        int d = idx >> 2, q = idx & 3;
        *(float4*)&As[idx * 4] = *(const float4*)&Wk[(size_t)d * CCH + bi * 16 + 4 * q];
        *(float4*)&Bs[idx * 4] = *(const float4*)&Wq[(size_t)d * CCH + bj * 16 + 4 * q];
    }
    __syncthreads();
    float acc = 0.f;
#pragma unroll 8
    for (int d = 0; d < D2; d++)
        acc += As[d * 16 + ti] * Bs[d * 16 + tj];
    GT[(size_t)(bi * 16 + ti) * CCH + bj * 16 + tj] = acc;
}

// ---- Kernel 2: per (b,s): v = avgpool64(ctx bin), M[b,:,s] = GT^T v ----
__global__ __launch_bounds__(384) void mv_k(const float* __restrict__ ctx,
                                            const float* __restrict__ GT,
                                            float* __restrict__ M) {
    __shared__ float v[CCH];
    int b = blockIdx.x / S2, s = blockIdx.x % S2;
    int t = threadIdx.x;
    int sy = s / 7, sx = s % 7;
    {
        const float* p = ctx + ((size_t)(b * CCH + t)) * HW + sy * 8 * WWD + sx * 8;
        float sum = 0.f;
#pragma unroll
        for (int r = 0; r < 8; r++) {
            float4 a = *(const float4*)(p + r * WWD);
            float4 c = *(const float4*)(p + r * WWD + 4);
            sum += a.x + a.y + a.z + a.w + c.x + c.y + c.z + c.w;
        }
        v[t] = sum * (1.f / 64.f);
    }
    __syncthreads();
    float acc = 0.f;
#pragma unroll 8
    for (int i = 0; i < CCH; i++)
        acc += v[i] * GT[(size_t)i * CCH + t];
    M[((size_t)(b * CCH + t)) * S2P + s] = acc;
    if (s < 3) M[((size_t)(b * CCH + t)) * S2P + 49 + s] = 0.f;
}

// ---- Kernel 3: scores = x^T M (16-way K-split), softmax(49), dyn = Wwd*A ----
// 256 thr, 16 px/block, grid B*196. Roles: pxg=t&3, sg=(t>>2)&3, slice=t>>4.
__global__ __launch_bounds__(256) void attn_k(const float* __restrict__ x,
                                              const float* __restrict__ M,
                                              const float* __restrict__ Wwd,
                                              float* __restrict__ dyn) {
    __shared__ __align__(16) float smem[96 * XSP + 96 * S2P];  // xs | Ms ; red aliases
    __shared__ __align__(16) float sc[16 * S2P];
    __shared__ __align__(16) float wl[K2 * S2P];
    float* xs  = smem;               // [96][20]
    float* Ms  = smem + 96 * XSP;    // [96][52]
    float* red = smem;               // [4][16][52] = 3328 floats, aliases xs+Ms head

    int b  = blockIdx.x / 196;
    int n0 = (blockIdx.x % 196) * 16;
    int t  = threadIdx.x;
    int pxg = t & 3, sg = (t >> 2) & 3, slice = t >> 4;

    float4 acc4[4][4];
#pragma unroll
    for (int k = 0; k < 4; k++)
#pragma unroll
        for (int j = 0; j < 4; j++) acc4[k][j] = make_float4(0.f, 0.f, 0.f, 0.f);

    const float* xb = x + (size_t)b * CCH * HW + n0;
    const float* Mb = M + (size_t)b * CCH * S2P;

    for (int ch = 0; ch < 4; ch++) {
        int c0 = ch * 96;
        // stage xs: 384 f4, fixed unroll (256 + 128)
        {
            int idx = t;
            int r = idx >> 2, cq = idx & 3;
            float4 val = *(const float4*)&xb[(size_t)(c0 + r) * HW + 4 * cq];
            *(float4*)&xs[r * XSP + 4 * cq] = val;
            if (t < 128) {
                int idx2 = t + 256;
                int r2 = idx2 >> 2, cq2 = idx2 & 3;
                float4 v2 = *(const float4*)&xb[(size_t)(c0 + r2) * HW + 4 * cq2];
                *(float4*)&xs[r2 * XSP + 4 * cq2] = v2;
            }
        }
        // stage Ms: 1248 f4 = 4*256 + 224, fixed unroll
        {
            const float* src = Mb + (size_t)c0 * S2P;
#pragma unroll
            for (int k = 0; k < 4; k++) {
                int idx = t + 256 * k;
                *(float4*)&Ms[4 * idx] = *(const float4*)&src[4 * idx];
            }
            if (t < 224) {
                int idx = t + 1024;
                *(float4*)&Ms[4 * idx] = *(const float4*)&src[4 * idx];
            }
        }
        __syncthreads();
        int rbase = 6 * slice;
#pragma unroll
        for (int m = 0; m < 6; m++) {
            int r = rbase + m;
            const float4 xv = *(const float4*)&xs[r * XSP + 4 * pxg];
#pragma unroll
            for (int k = 0; k < 3; k++) {
                int g = sg + 4 * k;
                const float4 mv = *(const float4*)&Ms[r * S2P + 4 * g];
                acc4[k][0].x += mv.x * xv.x; acc4[k][0].y += mv.x * xv.y;
                acc4[k][0].z += mv.x * xv.z; acc4[k][0].w += mv.x * xv.w;
                acc4[k][1].x += mv.y * xv.x; acc4[k][1].y += mv.y * xv.y;
                acc4[k][1].z += mv.y * xv.z; acc4[k][1].w += mv.y * xv.w;
                acc4[k][2].x += mv.z * xv.x; acc4[k][2].y += mv.z * xv.y;
                acc4[k][2].z += mv.z * xv.z; acc4[k][2].w += mv.z * xv.w;
                acc4[k][3].x += mv.w * xv.x; acc4[k][3].y += mv.w * xv.y;
                acc4[k][3].z += mv.w * xv.z; acc4[k][3].w += mv.w * xv.w;
            }
            if (sg == 0) {
                const float4 mv = *(const float4*)&Ms[r * S2P + 48];
                acc4[3][0].x += mv.x * xv.x; acc4[3][0].y += mv.x * xv.y;
                acc4[3][0].z += mv.x * xv.z; acc4[3][0].w += mv.x * xv.w;
                acc4[3][1].x += mv.y * xv.x; acc4[3][1].y += mv.y * xv.y;
                acc4[3][1].z += mv.y * xv.z; acc4[3][1].w += mv.y * xv.w;
                acc4[3][2].x += mv.z * xv.x; acc4[3][2].y += mv.z * xv.y;
                acc4[3][2].z += mv.z * xv.z; acc4[3][2].w += mv.z * xv.w;
                acc4[3][3].x += mv.w * xv.x; acc4[3][3].y += mv.w * xv.y;
                acc4[3][3].z += mv.w * xv.z; acc4[3][3].w += mv.w * xv.w;
            }
        }
        __syncthreads();
    }

    // in-wave reduce across 4 slice-groups (lane^16, lane^32)
#pragma unroll
    for (int k = 0; k < 4; k++)
#pragma unroll
        for (int j = 0; j < 4; j++) {
            acc4[k][j].x += __shfl_xor(acc4[k][j].x, 16);
            acc4[k][j].y += __shfl_xor(acc4[k][j].y, 16);
            acc4[k][j].z += __shfl_xor(acc4[k][j].z, 16);
            acc4[k][j].w += __shfl_xor(acc4[k][j].w, 16);
            acc4[k][j].x += __shfl_xor(acc4[k][j].x, 32);
            acc4[k][j].y += __shfl_xor(acc4[k][j].y, 32);
            acc4[k][j].z += __shfl_xor(acc4[k][j].z, 32);
            acc4[k][j].w += __shfl_xor(acc4[k][j].w, 32);
        }

    // wave partials -> red[wave][16px][52]
    if ((t & 63) < 16) {
        int wv = t >> 6;
        float* rb = red + (size_t)wv * 16 * S2P;
#pragma unroll
        for (int k = 0; k < 4; k++) {
            int g = sg + 4 * k;
            if (g < 13) {
                *(float4*)&rb[(4 * pxg + 0) * S2P + 4 * g] =
                    make_float4(acc4[k][0].x, acc4[k][1].x, acc4[k][2].x, acc4[k][3].x);
                *(float4*)&rb[(4 * pxg + 1) * S2P + 4 * g] =
                    make_float4(acc4[k][0].y, acc4[k][1].y, acc4[k][2].y, acc4[k][3].y);
                *(float4*)&rb[(4 * pxg + 2) * S2P + 4 * g] =
                    make_float4(acc4[k][0].z, acc4[k][1].z, acc4[k][2].z, acc4[k][3].z);
                *(float4*)&rb[(4 * pxg + 3) * S2P + 4 * g] =
                    make_float4(acc4[k][0].w, acc4[k][1].w, acc4[k][2].w, acc4[k][3].w);
            }
        }
    }
    __syncthreads();

    // final reduce over 4 waves -> sc
    if (t < 208) {
        int px = t / 13, q = t - px * 13;
        float4 ssum = make_float4(0.f, 0.f, 0.f, 0.f);
#pragma unroll
        for (int wv = 0; wv < 4; wv++) {
            float4 vv = *(float4*)&red[(size_t)(wv * 16 + px) * S2P + 4 * q];
            ssum.x += vv.x; ssum.y += vv.y; ssum.z += vv.z; ssum.w += vv.w;
        }
        *(float4*)&sc[px * S2P + 4 * q] = ssum;
    }
    __syncthreads();

    // softmax (threads < 128: 8 lanes per pixel) | Wwd staging (threads >= 128)
    if (t < 128) {
        int px = t >> 3, li = t & 7;
        float mx = -3.4e38f;
#pragma unroll
        for (int k = 0; k < 7; k++) { int s = li + 8 * k; if (s < S2) mx = fmaxf(mx, sc[px * S2P + s]); }
        mx = fmaxf(mx, __shfl_xor(mx, 1, 8));
        mx = fmaxf(mx, __shfl_xor(mx, 2, 8));
        mx = fmaxf(mx, __shfl_xor(mx, 4, 8));
        float e[7]; float sum = 0.f;
#pragma unroll
        for (int k = 0; k < 7; k++) {
            int s = li + 8 * k;
            if (s < S2) { e[k] = __expf(sc[px * S2P + s] - mx); sum += e[k]; }
        }
        sum += __shfl_xor(sum, 1, 8);
        sum += __shfl_xor(sum, 2, 8);
        sum += __shfl_xor(sum, 4, 8);
        float inv = 1.f / sum;
#pragma unroll
        for (int k = 0; k < 7; k++) {
            int s = li + 8 * k;
            if (s < S2) sc[px * S2P + s] = e[k] * inv;
        }
    } else {
        int u = t - 128;
#pragma unroll
        for (int k = 0; k < 10; k++) {
            int i = u + 128 * k;
            int j = i / S2P, ss = i - j * S2P;
            wl[i] = (ss < S2) ? Wwd[j * S2 + ss] : 0.f;
        }
        if (u < 20) {
            int i = u + 1280;
            int j = i / S2P, ss = i - j * S2P;
            wl[i] = (ss < S2) ? Wwd[j * S2 + ss] : 0.f;
        }
    }
    __syncthreads();

    // dyn[b,j,n0+px] = sum_s wl[j,s]*sc[px,s]   (400 outs: 256 + 144)
    float* dynb = dyn + (size_t)b * K2 * HW + n0;
#pragma unroll
    for (int pass = 0; pass < 2; pass++) {
        int o = t + 256 * pass;
        if (pass == 0 || t < 144) {
            int j = o >> 4, px = o & 15;
            float a = 0.f;
#pragma unroll
            for (int q = 0; q < 13; q++) {
                float4 wv = *(float4*)&wl[j * S2P + 4 * q];
                float4 pv = *(float4*)&sc[px * S2P + 4 * q];
                a += wv.x * pv.x + wv.y * pv.y + wv.z * pv.z + wv.w * pv.w;
            }
            dynb[(size_t)j * HW + px] = a;
        }
    }
}

// ---- Kernel 4: 5x5 dynamic stencil; 16 ch x 8-row stripe; 2 rows/thread ----
__global__ __launch_bounds__(256, 3) void out_k(const float* __restrict__ x,
                                                const float* __restrict__ dyn,
                                                float* __restrict__ out) {
    __shared__ float xt[16][12][60];
    int blk    = blockIdx.x;
    int stripe = blk % 7;
    int cg     = (blk / 7) % 24;
    int b      = blk / (7 * 24);
    int h0 = stripe * 8;
    int c0 = cg * 16;
    int t  = threadIdx.x;
    const float* xb = x + ((size_t)(b * CCH + c0)) * HW;

    if (t < 192) {
        int cc = t / 12, r = t % 12;
        xt[cc][r][0] = 0.f; xt[cc][r][1] = 0.f;
        xt[cc][r][58] = 0.f; xt[cc][r][59] = 0.f;
    }
#pragma unroll
    for (int k = 0; k < 11; k++) {
        int idx = t + 256 * k;
        if (k < 10 || t < 128) {
            int cc  = idx / 168;
            int rem = idx - cc * 168;
            int r   = rem / 14;
            int q   = rem - r * 14;
            int h   = h0 - 2 + r;
            float4 v = make_float4(0.f, 0.f, 0.f, 0.f);
            if ((unsigned)h < (unsigned)HH)
                v = *(const float4*)&xb[(size_t)cc * HW + h * WWD + 4 * q];
            xt[cc][r][2 + 4 * q + 0] = v.x;
            xt[cc][r][2 + 4 * q + 1] = v.y;
            xt[cc][r][2 + 4 * q + 2] = v.z;
            xt[cc][r][2 + 4 * q + 3] = v.w;
        }
    }

    bool act = t < 224;
    int w = t % 56;
    int u = t / 56;                  // 0..3 -> rows 2u, 2u+1
    int n = (h0 + 2 * u) * WWD + w;
    float dv0[K2], dv1[K2];
    if (act) {
        const float* db = dyn + (size_t)b * K2 * HW + n;
#pragma unroll
        for (int j = 0; j < K2; j++) {
            dv0[j] = db[(size_t)j * HW];
            dv1[j] = db[(size_t)j * HW + WWD];
        }
    }
    __syncthreads();
    if (!act) return;

    float* ob = out + ((size_t)(b * CCH + c0)) * HW + n;
#pragma unroll
    for (int cc = 0; cc < 16; cc++) {
        float a0 = 0.f, a1 = 0.f;
#pragma unroll
        for (int rr = 0; rr < 6; rr++) {
            int lr = 2 * u + rr;
            float v0 = xt[cc][lr][w + 0];
            float v1 = xt[cc][lr][w + 1];
            float v2 = xt[cc][lr][w + 2];
            float v3 = xt[cc][lr][w + 3];
            float v4 = xt[cc][lr][w + 4];
            if (rr < 5) {
                int o5 = rr * 5;
                a0 += v0 * dv0[o5] + v1 * dv0[o5 + 1] + v2 * dv0[o5 + 2]
                    + v3 * dv0[o5 + 3] + v4 * dv0[o5 + 4];
            }
            if (rr >= 1) {
                int o5 = (rr - 1) * 5;
                a1 += v0 * dv1[o5] + v1 * dv1[o5 + 1] + v2 * dv1[o5 + 2]
                    + v3 * dv1[o5 + 3] + v4 * dv1[o5 + 4];
            }
        }
        ob[(size_t)cc * HW] = a0;
        ob[(size_t)cc * HW + WWD] = a1;
    }
}

extern "C" void kernel_launch(void* const* d_in, const int* in_sizes, int n_in,
                              void* d_out, int out_size, void* d_ws, size_t ws_size,
                              hipStream_t stream) {
    const float* x   = (const float*)d_in[0];
    const float* ctx = (const float*)d_in[1];
    const float* Wq  = (const float*)d_in[2];
    const float* Wk  = (const float*)d_in[3];
    const float* Wwd = (const float*)d_in[4];
    float* out = (float*)d_out;
    float* ws  = (float*)d_ws;

    float* GT  = ws;                    // 384*384            = 147456
    float* M   = ws + 147456;           // B*384*52           =  79872
    float* dyn = ws + 147456 + 79872;   // B*25*3136          = 313600

    gt_k<<<24 * 24, 256, 0, stream>>>(Wk, Wq, GT);
    mv_k<<<BB * S2, 384, 0, stream>>>(ctx, GT, M);
    attn_k<<<BB * 196, 256, 0, stream>>>(x, M, Wwd, dyn);
    out_k<<<BB * 24 * 7, 256, 0, stream>>>(x, dyn, out);
}